// Round 13
// baseline (577.546 us; speedup 1.0000x reference)
//
#include <hip/hip_runtime.h>

// SimpleRNN: x(256,2048,8) f32, h(1,256,128), W_ih(128,8), W_hh(128,128),
// b_ih(128), b_hh(128), W_head(1,128), b_head(1)
// out = [pred(256) | last_step_features(256,128) | h_n(256,128)]  (f32)
//
// R11 = R10 (576us, best) + ONE change: weights laundered through one-time
// v_mov_b32 inline asm at init. An asm def is OPAQUE to LLVM's
// rematerializer -> the values CANNOT be re-loaded in the loop; they must
// stay live. amdgpu_waves_per_eu(1,1) gives the 512-VGPR budget (kernel is
// already 1 wave/SIMD) so the RA keeps them in registers, not scratch.
// R0-R10 evidence: every raw-load weight copy was remat'd (VGPR 32-52,
// ~64KB/step L1 thrash = the measured step time); asm/cvt-produced values
// stayed resident (R6: VGPR 80, R7: 44).

typedef float f32x2 __attribute__((ext_vector_type(2)));
typedef float f32x4 __attribute__((ext_vector_type(4)));

#define BB 256
#define TT 2048
#define II 8
#define HH 128
#define THREADS 256

// v_pk_fma_f32, src0 LO/HI broadcast to both halves (R4-verified encodings)
#define PK_FMA_LO(acc, hp, wp) \
    asm("v_pk_fma_f32 %0, %1, %2, %0 op_sel:[0,0,0] op_sel_hi:[0,1,1]" \
        : "+v"(acc) : "v"(hp), "v"(wp))
#define PK_FMA_HI(acc, hp, wp) \
    asm("v_pk_fma_f32 %0, %1, %2, %0 op_sel:[1,0,0] op_sel_hi:[1,1,1]" \
        : "+v"(acc) : "v"(hp), "v"(wp))

__device__ __forceinline__ float quad_sum(float x) {
    // xor1 + xor2 butterfly within each aligned 4-lane quad (DPP only)
    int xi = __builtin_bit_cast(int, x);
    int y1 = __builtin_amdgcn_update_dpp(0, xi, 0xB1, 0xF, 0xF, true); // [1,0,3,2]
    float s1 = x + __builtin_bit_cast(float, y1);
    int s1i = __builtin_bit_cast(int, s1);
    int y2 = __builtin_amdgcn_update_dpp(0, s1i, 0x4E, 0xF, 0xF, true); // [2,3,0,1]
    return s1 + __builtin_bit_cast(float, y2);
}

// one-time laundering: asm def is not rematerializable -> value stays live
__device__ __forceinline__ f32x2 launder2(f32x2 v) {
    f32x2 r;
    asm("v_mov_b32 %0, %2\n\tv_mov_b32 %1, %3"
        : "=v"(r.x), "=v"(r.y) : "v"(v.x), "v"(v.y));
    return r;
}

__global__ void
__launch_bounds__(THREADS, 1)
__attribute__((amdgpu_waves_per_eu(1, 1)))
rnn_v11_kernel(const float* __restrict__ x,
               const float* __restrict__ h0,
               const float* __restrict__ W_ih,
               const float* __restrict__ W_hh,
               const float* __restrict__ b_ih,
               const float* __restrict__ b_hh,
               const float* __restrict__ W_head,
               const float* __restrict__ b_head,
               float* __restrict__ out)
{
    __shared__ __align__(16) float h_lds[2][HH];   // ping-pong hidden state
    __shared__ float part[HH];

    const int b    = blockIdx.x;
    const int tid  = threadIdx.x;
    const int w    = tid >> 6;        // wave 0..3
    const int lane = tid & 63;
    const int jg   = lane >> 2;       // 0..15
    const int kc   = lane & 3;        // 0..3 (32-k chunk)
    const int j0   = w * 32 + jg * 2; // this lane's 2 outputs: j0, j0+1

    // ---- weights in READ order (rotation (i+2kc)&7 baked into slot index):
    // wj[4i+c] = (W_hh[j0][kc*32+4m+c], W_hh[j0+1][kc*32+4m+c]), m=(i+2kc)&7
    f32x2 wj[32];
    {
        const float* r0 = W_hh + (size_t)j0 * HH + kc * 32;
        const float* r1 = r0 + HH;
        #pragma unroll
        for (int i = 0; i < 8; ++i) {
            const int m = (i + 2 * kc) & 7;
            #pragma unroll
            for (int c = 0; c < 4; ++c)
                wj[4 * i + c] = launder2((f32x2){r0[4 * m + c], r1[4 * m + c]});
        }
    }
    f32x2 wx0 = launder2((f32x2){W_ih[j0 * II + 2 * kc],
                                 W_ih[(j0 + 1) * II + 2 * kc]});
    f32x2 wx1 = launder2((f32x2){W_ih[j0 * II + 2 * kc + 1],
                                 W_ih[(j0 + 1) * II + 2 * kc + 1]});
    f32x2 bias2 = launder2((f32x2){0.25f * (b_ih[j0] + b_hh[j0]),
                                   0.25f * (b_ih[j0 + 1] + b_hh[j0 + 1])});

    if (tid < HH) h_lds[0][tid] = h0[b * HH + tid];
    __syncthreads();

    // x: direct global reads, 2-step register pipeline (L2-resident; vmcnt
    // never drained in-loop so these float across barriers)
    const float* xk = x + (size_t)b * TT * II + 2 * kc;
    f32x2 xe = *(const f32x2*)(xk + 0 * II);
    f32x2 xo = *(const f32x2*)(xk + 1 * II);

    #define STEP(XV, RBUF, TN)                                                   \
    {                                                                            \
        f32x2 a0 = bias2;                                                        \
        f32x2 a1 = (f32x2){0.f, 0.f};                                            \
        f32x2 a2 = (f32x2){0.f, 0.f};                                            \
        f32x2 a3 = (f32x2){0.f, 0.f};                                            \
        PK_FMA_LO(a0, XV, wx0);          /* x[2kc]   * W_ih col for j0,j1 */     \
        PK_FMA_HI(a1, XV, wx1);          /* x[2kc+1] * W_ih col for j0,j1 */     \
        _Pragma("unroll")                                                        \
        for (int i = 0; i < 8; i += 2) {                                         \
            const f32x4 hva = *(const f32x4*)                                    \
                &h_lds[RBUF][kc * 32 + (((i + 0) + 2 * kc) & 7) * 4];            \
            const f32x4 hvb = *(const f32x4*)                                    \
                &h_lds[RBUF][kc * 32 + (((i + 1) + 2 * kc) & 7) * 4];            \
            const f32x2 ha01 = __builtin_shufflevector(hva, hva, 0, 1);          \
            const f32x2 ha23 = __builtin_shufflevector(hva, hva, 2, 3);          \
            const f32x2 hb01 = __builtin_shufflevector(hvb, hvb, 0, 1);          \
            const f32x2 hb23 = __builtin_shufflevector(hvb, hvb, 2, 3);          \
            PK_FMA_LO(a0, ha01, wj[4 * i + 0]);                                  \
            PK_FMA_HI(a1, ha01, wj[4 * i + 1]);                                  \
            PK_FMA_LO(a2, ha23, wj[4 * i + 2]);                                  \
            PK_FMA_HI(a3, ha23, wj[4 * i + 3]);                                  \
            PK_FMA_LO(a0, hb01, wj[4 * i + 4]);                                  \
            PK_FMA_HI(a1, hb01, wj[4 * i + 5]);                                  \
            PK_FMA_LO(a2, hb23, wj[4 * i + 6]);                                  \
            PK_FMA_HI(a3, hb23, wj[4 * i + 7]);                                  \
        }                                                                        \
        const f32x2 s2 = (a0 + a1) + (a2 + a3);   /* v_pk_add_f32 x3 */          \
        const float s0 = quad_sum(s2.x);                                         \
        const float s1 = quad_sum(s2.y);                                         \
        const float e0 = __builtin_amdgcn_exp2f(s0 * 2.8853900817779268f);       \
        const float e1 = __builtin_amdgcn_exp2f(s1 * 2.8853900817779268f);       \
        f32x2 hn;                                                                \
        hn.x = 1.0f - 2.0f * __builtin_amdgcn_rcpf(e0 + 1.0f);                   \
        hn.y = 1.0f - 2.0f * __builtin_amdgcn_rcpf(e1 + 1.0f);                   \
        if (kc == 0) *(f32x2*)&h_lds[(RBUF) ^ 1][j0] = hn;                       \
        { const int tn_ = (TN) < TT ? (TN) : (TT - 1);                           \
          XV = *(const f32x2*)(xk + (size_t)tn_ * II); }                         \
        asm volatile("s_waitcnt lgkmcnt(0)\n\ts_barrier" ::: "memory");          \
    }

    for (int t = 0; t < TT; t += 2) {
        STEP(xe, 0, t + 2)   // even step: reads buf0, writes buf1
        STEP(xo, 1, t + 3)   // odd  step: reads buf1, writes buf0
    }
    #undef STEP

    // ---- epilogue: final h in h_lds[0] (t=2047 odd wrote buf 0) ----
    if (tid < HH) {
        const float hl = h_lds[0][tid];
        out[BB + b * HH + tid]           = hl;   // last_step_features
        out[BB + BB * HH + b * HH + tid] = hl;   // h_n
        part[tid] = hl * W_head[tid];
    }
    __syncthreads();
    if (w == 0) {
        float s = part[lane] + part[lane + 64];
        #pragma unroll
        for (int off = 32; off > 0; off >>= 1) s += __shfl_down(s, off);
        if (lane == 0) out[b] = s + b_head[0];
    }
}

extern "C" void kernel_launch(void* const* d_in, const int* in_sizes, int n_in,
                              void* d_out, int out_size, void* d_ws, size_t ws_size,
                              hipStream_t stream) {
    const float* x      = (const float*)d_in[0];
    const float* h0     = (const float*)d_in[1];
    const float* W_ih   = (const float*)d_in[2];
    const float* W_hh   = (const float*)d_in[3];
    const float* b_ih   = (const float*)d_in[4];
    const float* b_hh   = (const float*)d_in[5];
    const float* W_head = (const float*)d_in[6];
    const float* b_head = (const float*)d_in[7];
    float* out = (float*)d_out;

    hipLaunchKernelGGL(rnn_v11_kernel, dim3(BB), dim3(THREADS), 0, stream,
                       x, h0, W_ih, W_hh, b_ih, b_hh, W_head, b_head, out);
}